// Round 3
// baseline (574.261 us; speedup 1.0000x reference)
//
#include <hip/hip_runtime.h>

// C51 distributional Q target: operand-swapped MFMA (D = W * X^T), each lane
// owns 4 consecutive FEATURES of one batch ROW; LN/SiLU/softmax in registers.
// R3: 512-thread blocks (8 waves, feature-eighth each), LDS squeezed to 53.4KB
// (H3 aliases dead H1; proj zeroed post-GEMM4) -> 3 blocks/CU = 24 waves/CU.

#define THREADS 512
#define PREP_THREADS 256

typedef __attribute__((ext_vector_type(8))) short short8v;
typedef __attribute__((ext_vector_type(4))) float f32x4;

__device__ __forceinline__ unsigned short f2bf(float f) {
  union { float f; unsigned u; } v; v.f = f;
  unsigned u = v.u;
  u += 0x7fffu + ((u >> 16) & 1u);   // RNE
  return (unsigned short)(u >> 16);
}
__device__ __forceinline__ unsigned pack2bf(float a, float b) {
  return (unsigned)f2bf(a) | ((unsigned)f2bf(b) << 16);
}

// ---------------- prep: weights fp32 [K][N] -> bf16 [N][K] in ws -------------
// W1T @0 (512x160), W2T @81920 (256x512), W3T @212992 (128x256),
// W4T @245760 (256x128, rows n>=251 zero-padded)
__global__ void prep_kernel(const float* __restrict__ W1, const float* __restrict__ W2,
                            const float* __restrict__ W3, const float* __restrict__ W4,
                            unsigned short* __restrict__ ws) {
  int i = blockIdx.x * PREP_THREADS + threadIdx.x;
  if (i < 81920) {
    int n = i / 160, k = i - n * 160;
    ws[i] = f2bf(W1[k * 512 + n]);
  } else if (i < 212992) {
    int j = i - 81920; int n = j >> 9, k = j & 511;
    ws[i] = f2bf(W2[k * 256 + n]);
  } else if (i < 245760) {
    int j = i - 212992; int n = j >> 8, k = j & 255;
    ws[i] = f2bf(W3[k * 128 + n]);
  } else if (i < 278528) {
    int j = i - 245760; int n = j >> 7, k = j & 127;
    ws[i] = (n < 251) ? f2bf(W4[k * 251 + n]) : (unsigned short)0;
  }
}

// LDS layout (bytes), aliased:
//  A @0     (32768): H1 bf16 [32][512] swz  |  H3 bf16 [32][128] swz @0
//                    |  proj f32 [32][251] (zeroed AFTER GEMM4's H3 reads)
//  B @32768 (16384): X bf16 [32][160] swz   |  H2 bf16 [32][256] swz
//  zs @49152 (1024), b4 @50176 (1024), red @51200 (32*17*4 = 2176)
#define OFF_A   0
#define OFF_B   32768
#define OFF_ZS  49152
#define OFF_B4  50176
#define OFF_RED 51200
#define LDS_TOTAL 53376

// GEMM: acc[ft][rt] += WT[fbase+ft*16+..][k] * H[rt*16+..][k]
// MFMA 16x16x32 bf16, A = weight rows (m=feature), B = act rows (n=batch row).
// D: lane&15 = batch row in tile, (lane>>4)*4+reg = feature in tile.
template<int KD, int NFT>
__device__ __forceinline__ void gemm_w(const unsigned short* __restrict__ WT,
                                       const unsigned char* __restrict__ Hb,
                                       int fbase, f32x4 (&acc)[NFT][2]) {
  const int lane = threadIdx.x & 63;
  const int lm = lane & 15, kg = lane >> 4;
#pragma unroll 4
  for (int ks = 0; ks < KD / 32; ++ks) {
    const int kk = ks * 32 + kg * 8;
    short8v b[2];
#pragma unroll
    for (int rt = 0; rt < 2; ++rt) {
      const int r = rt * 16 + lm;
      int byte = r * (KD * 2) + kk * 2;
      byte ^= ((r & 7) << 4);
      b[rt] = *(const short8v*)(Hb + byte);
    }
#pragma unroll
    for (int ft = 0; ft < NFT; ++ft) {
      const short8v a = *(const short8v*)(WT + (size_t)(fbase + ft * 16 + lm) * KD + kk);
      acc[ft][0] = __builtin_amdgcn_mfma_f32_16x16x32_bf16(a, b[0], acc[ft][0], 0, 0, 0);
      acc[ft][1] = __builtin_amdgcn_mfma_f32_16x16x32_bf16(a, b[1], acc[ft][1], 0, 0, 0);
    }
  }
}

// bias + LayerNorm + SiLU entirely in registers, then one packed b64 store
// per (ft, rt) into swizzled LDS [32][ND] bf16. 8 waves reduce via redL
// (stride 17 floats per row to dodge bank conflicts).
template<int ND, int NFT>
__device__ __forceinline__ void ln_silu_store(
    f32x4 (&acc)[NFT][2],
    const float* __restrict__ bias, const float* __restrict__ g,
    const float* __restrict__ be, unsigned char* __restrict__ Hb,
    float* __restrict__ redL, int fbase, int fq)
{
  const int lane = threadIdx.x & 63;
  const int lm = lane & 15, kg = lane >> 4;
  float s[2] = {0.f, 0.f}, q[2] = {0.f, 0.f};
#pragma unroll
  for (int ft = 0; ft < NFT; ++ft) {
    const int f0 = fbase + ft * 16 + kg * 4;
    const f32x4 bb = *(const f32x4*)(bias + f0);
#pragma unroll
    for (int rt = 0; rt < 2; ++rt)
#pragma unroll
      for (int rg = 0; rg < 4; ++rg) {
        float x = acc[ft][rt][rg] + bb[rg];
        acc[ft][rt][rg] = x;
        s[rt] += x; q[rt] += x * x;
      }
  }
#pragma unroll
  for (int rt = 0; rt < 2; ++rt) {
    s[rt] += __shfl_xor(s[rt], 16); s[rt] += __shfl_xor(s[rt], 32);
    q[rt] += __shfl_xor(q[rt], 16); q[rt] += __shfl_xor(q[rt], 32);
  }
  if (lane < 16) {
#pragma unroll
    for (int rt = 0; rt < 2; ++rt) {
      redL[(rt * 16 + lm) * 17 + fq * 2    ] = s[rt];
      redL[(rt * 16 + lm) * 17 + fq * 2 + 1] = q[rt];
    }
  }
  __syncthreads();
  float mean[2], rstd[2];
#pragma unroll
  for (int rt = 0; rt < 2; ++rt) {
    const int row = rt * 16 + lm;
    float S = 0.f, Q = 0.f;
#pragma unroll
    for (int w = 0; w < 8; ++w) {
      S += redL[row * 17 + w * 2];
      Q += redL[row * 17 + w * 2 + 1];
    }
    float m = S * (1.0f / ND);
    float v = Q * (1.0f / ND) - m * m;
    mean[rt] = m; rstd[rt] = rsqrtf(v + 1e-5f);
  }
#pragma unroll
  for (int ft = 0; ft < NFT; ++ft) {
    const int f0 = fbase + ft * 16 + kg * 4;
    const f32x4 g4 = *(const f32x4*)(g + f0);
    const f32x4 e4 = *(const f32x4*)(be + f0);
#pragma unroll
    for (int rt = 0; rt < 2; ++rt) {
      const int row = rt * 16 + lm;
      float h[4];
#pragma unroll
      for (int rg = 0; rg < 4; ++rg) {
        float y = (acc[ft][rt][rg] - mean[rt]) * rstd[rt] * g4[rg] + e4[rg];
        h[rg] = y * (1.0f / (1.0f + __expf(-y)));
      }
      uint2 w; w.x = pack2bf(h[0], h[1]); w.y = pack2bf(h[2], h[3]);
      int byte = row * (ND * 2) + f0 * 2;
      byte ^= ((row & 7) << 4);
      *(uint2*)(Hb + byte) = w;
    }
  }
}

__global__ __launch_bounds__(THREADS, 6) void fused_kernel(
    const float* __restrict__ obs, const float* __restrict__ actions,
    const float* __restrict__ rewards, const float* __restrict__ bootstrap,
    const float* __restrict__ discount, const float* __restrict__ q_support,
    const float* __restrict__ b1, const float* __restrict__ g1, const float* __restrict__ be1,
    const float* __restrict__ b2, const float* __restrict__ g2, const float* __restrict__ be2,
    const float* __restrict__ b3, const float* __restrict__ g3, const float* __restrict__ be3,
    const float* __restrict__ b4,
    const unsigned short* __restrict__ ws,
    float* __restrict__ out)
{
  __shared__ __align__(16) unsigned char smem[LDS_TOTAL];
  const int tid  = threadIdx.x;
  const int fq   = tid >> 6;          // wave = feature-eighth, 0..7
  const int lane = tid & 63;
  const int lm   = lane & 15;
  const int kg   = lane >> 4;
  const int row0 = blockIdx.x * 32;

  const unsigned short* W1T = ws;
  const unsigned short* W2T = ws + 81920;
  const unsigned short* W3T = ws + 212992;
  const unsigned short* W4T = ws + 245760;

  float* zsL  = (float*)(smem + OFF_ZS);
  float* b4L  = (float*)(smem + OFF_B4);
  float* redL = (float*)(smem + OFF_RED);

  // per-row scalars straight to registers (each lane owns rows rt*16+lm)
  float rw[2], bt[2], dc[2];
#pragma unroll
  for (int rt = 0; rt < 2; ++rt) {
    const int r = row0 + rt * 16 + lm;
    rw[rt] = rewards[r]; bt[rt] = bootstrap[r]; dc[rt] = discount[r];
  }

  // stage q_support / b4 (padded to 256, avoids OOB vector loads)
  if (tid < 256) {
    zsL[tid] = (tid < 251) ? q_support[tid] : 0.f;
    b4L[tid] = (tid < 251) ? b4[tid] : 0.f;
  }

  // stage X = concat(obs, actions) bf16 [32][160], swizzled (1280 float4)
  {
    unsigned char* Xb = smem + OFF_B;
    for (int qq = tid; qq < 1280; qq += THREADS) {
      const int r  = qq / 40;
      const int c4 = (qq - r * 40) * 4;
      float4 v;
      if (c4 < 128) v = *(const float4*)(obs + (size_t)(row0 + r) * 128 + c4);
      else          v = *(const float4*)(actions + (size_t)(row0 + r) * 32 + (c4 - 128));
      uint2 w; w.x = pack2bf(v.x, v.y); w.y = pack2bf(v.z, v.w);
      int byte = r * 320 + c4 * 2;
      byte ^= ((r & 7) << 4);
      *(uint2*)(Xb + byte) = w;
    }
  }
  __syncthreads();

  // ---- layer 1: 512 feats, K=160; 64 feats/wave ----
  f32x4 acc1[4][2];
#pragma unroll
  for (int i = 0; i < 4; ++i) { acc1[i][0] = f32x4{0,0,0,0}; acc1[i][1] = f32x4{0,0,0,0}; }
  gemm_w<160, 4>(W1T, smem + OFF_B, fq * 64, acc1);
  ln_silu_store<512, 4>(acc1, b1, g1, be1, smem + OFF_A, redL, fq * 64, fq);
  __syncthreads();

  // ---- layer 2: 256 feats, K=512; 32 feats/wave ----
  f32x4 acc2[2][2];
#pragma unroll
  for (int i = 0; i < 2; ++i) { acc2[i][0] = f32x4{0,0,0,0}; acc2[i][1] = f32x4{0,0,0,0}; }
  gemm_w<512, 2>(W2T, smem + OFF_A, fq * 32, acc2);
  ln_silu_store<256, 2>(acc2, b2, g2, be2, smem + OFF_B, redL, fq * 32, fq);
  __syncthreads();

  // ---- layer 3: 128 feats, K=256; 16 feats/wave; H3 aliases dead H1 @A[0:8K]
  f32x4 acc3[1][2];
  acc3[0][0] = f32x4{0,0,0,0}; acc3[0][1] = f32x4{0,0,0,0};
  gemm_w<256, 1>(W3T, smem + OFF_B, fq * 16, acc3);
  ln_silu_store<128, 1>(acc3, b3, g3, be3, smem + OFF_A, redL, fq * 16, fq);
  __syncthreads();

  // ---- layer 4: logits, 256pad feats, K=128; 32 feats/wave ----
  f32x4 acc4[2][2];
#pragma unroll
  for (int i = 0; i < 2; ++i) { acc4[i][0] = f32x4{0,0,0,0}; acc4[i][1] = f32x4{0,0,0,0}; }
  gemm_w<128, 2>(W4T, smem + OFF_A, fq * 32, acc4);

  float lv[2][2][4];
#pragma unroll
  for (int ft = 0; ft < 2; ++ft) {
    const int f0 = fq * 32 + ft * 16 + kg * 4;
    const f32x4 bb = *(const f32x4*)(b4L + f0);
#pragma unroll
    for (int rt = 0; rt < 2; ++rt)
#pragma unroll
      for (int rg = 0; rg < 4; ++rg) {
        const int f = f0 + rg;
        lv[ft][rt][rg] = (f < 251) ? (acc4[ft][rt][rg] + bb[rg]) : -1e30f;
      }
  }

  // ---- softmax over 251 features per row (stride-9 padded reduction) ----
#pragma unroll
  for (int rt = 0; rt < 2; ++rt) {
    float m = lv[0][rt][0];
#pragma unroll
    for (int ft = 0; ft < 2; ++ft)
#pragma unroll
      for (int rg = 0; rg < 4; ++rg) m = fmaxf(m, lv[ft][rt][rg]);
    m = fmaxf(m, __shfl_xor(m, 16));
    m = fmaxf(m, __shfl_xor(m, 32));
    if (lane < 16) redL[(rt * 16 + lm) * 9 + fq] = m;
  }
  __syncthreads();   // also: all waves are past GEMM4's H3 reads

  // zero proj buffer (region A; overwrites H3 area too — H3 is dead now)
  float* projL = (float*)(smem + OFF_A);
  for (int i = tid; i < 32 * 251; i += THREADS) projL[i] = 0.f;

  float gm[2];
#pragma unroll
  for (int rt = 0; rt < 2; ++rt) {
    const int row = rt * 16 + lm;
    float m = redL[row * 9];
#pragma unroll
    for (int w = 1; w < 8; ++w) m = fmaxf(m, redL[row * 9 + w]);
    gm[rt] = m;
  }
  __syncthreads();   // redL reuse
#pragma unroll
  for (int rt = 0; rt < 2; ++rt) {
    float E = 0.f;
#pragma unroll
    for (int ft = 0; ft < 2; ++ft)
#pragma unroll
      for (int rg = 0; rg < 4; ++rg) {
        float e = __expf(lv[ft][rt][rg] - gm[rt]);
        lv[ft][rt][rg] = e;
        E += e;
      }
    E += __shfl_xor(E, 16); E += __shfl_xor(E, 32);
    if (lane < 16) redL[(rt * 16 + lm) * 9 + fq] = E;
  }
  __syncthreads();
  float inv[2];
#pragma unroll
  for (int rt = 0; rt < 2; ++rt) {
    const int row = rt * 16 + lm;
    float E = 0.f;
#pragma unroll
    for (int w = 0; w < 8; ++w) E += redL[row * 9 + w];
    inv[rt] = 1.0f / E;
  }

  // ---- C51 projection scatter (bit-exact bin math vs numpy) ----
  constexpr float DZF = 20.0f / 250.0f;
#pragma unroll
  for (int ft = 0; ft < 2; ++ft) {
    const int f0 = fq * 32 + ft * 16 + kg * 4;
    const f32x4 z4 = *(const f32x4*)(zsL + f0);
#pragma unroll
    for (int rt = 0; rt < 2; ++rt) {
      const int base = (rt * 16 + lm) * 251;
      const float bd = __fmul_rn(bt[rt], dc[rt]);
#pragma unroll
      for (int rg = 0; rg < 4; ++rg) {
        const int f = f0 + rg;
        if (f < 251) {
          const float p = lv[ft][rt][rg] * inv[rt];
          float t = __fadd_rn(rw[rt], __fmul_rn(bd, z4[rg]));
          t = fminf(fmaxf(t, -10.0f), 10.0f);
          const float bfr = __fdiv_rn(__fsub_rn(t, -10.0f), DZF);
          const float fl = floorf(bfr), fu = ceilf(bfr);
          int l = (int)fl, u = (int)fu;
          if (fl == fu) { if (l > 0) --l; else ++u; }
          atomicAdd(projL + base + l, p * ((float)u - bfr));
          atomicAdd(projL + base + u, p * (bfr - (float)l));
        }
      }
    }
  }
  __syncthreads();

  // ---- write out: block slice contiguous (32*251 floats = 2008 float4) ----
  const float4* ps = (const float4*)projL;
  float4* po = (float4*)(out + (size_t)row0 * 251);
  for (int i = tid; i < 2008; i += THREADS) po[i] = ps[i];
}

extern "C" void kernel_launch(void* const* d_in, const int* in_sizes, int n_in,
                              void* d_out, int out_size, void* d_ws, size_t ws_size,
                              hipStream_t stream) {
  const float* obs  = (const float*)d_in[0];
  const float* act  = (const float*)d_in[1];
  const float* rew  = (const float*)d_in[2];
  const float* boot = (const float*)d_in[3];
  const float* disc = (const float*)d_in[4];
  const float* zs   = (const float*)d_in[5];
  const float* W1   = (const float*)d_in[6];
  const float* b1   = (const float*)d_in[7];
  const float* g1   = (const float*)d_in[8];
  const float* be1  = (const float*)d_in[9];
  const float* W2   = (const float*)d_in[10];
  const float* b2   = (const float*)d_in[11];
  const float* g2   = (const float*)d_in[12];
  const float* be2  = (const float*)d_in[13];
  const float* W3   = (const float*)d_in[14];
  const float* b3   = (const float*)d_in[15];
  const float* g3   = (const float*)d_in[16];
  const float* be3  = (const float*)d_in[17];
  const float* W4   = (const float*)d_in[18];
  const float* b4   = (const float*)d_in[19];
  unsigned short* wsp = (unsigned short*)d_ws;

  const int Bn = in_sizes[2];          // batch = 131072
  prep_kernel<<<(278528 + PREP_THREADS - 1) / PREP_THREADS, PREP_THREADS, 0, stream>>>(
      W1, W2, W3, W4, wsp);
  fused_kernel<<<Bn / 32, THREADS, 0, stream>>>(obs, act, rew, boot, disc, zs,
      b1, g1, be1, b2, g2, be2, b3, g3, be3, b4, wsp, (float*)d_out);
}

// Round 4
// 507.972 us; speedup vs baseline: 1.1305x; 1.1305x over previous
//
#include <hip/hip_runtime.h>

// C51 distributional Q target: operand-swapped MFMA (D = W * X^T), each lane
// owns 4 consecutive FEATURES of one batch ROW; LN/SiLU/softmax in registers.
// R4: 256 threads / 4 waves / 32 rows (R2 per-wave ILP shapes) + 52.5KB LDS
// -> 3 blocks/CU (12 waves/CU), launch_bounds(256,3) (VGPR<=170), fully
// unrolled K loops with hoisted addressing (weight offs + parity LDS bases).

#define THREADS 256
#define PREP_THREADS 256

typedef __attribute__((ext_vector_type(8))) short short8v;
typedef __attribute__((ext_vector_type(4))) float f32x4;

__device__ __forceinline__ unsigned short f2bf(float f) {
  union { float f; unsigned u; } v; v.f = f;
  unsigned u = v.u;
  u += 0x7fffu + ((u >> 16) & 1u);   // RNE
  return (unsigned short)(u >> 16);
}
__device__ __forceinline__ unsigned pack2bf(float a, float b) {
  return (unsigned)f2bf(a) | ((unsigned)f2bf(b) << 16);
}

// ---------------- prep: weights fp32 [K][N] -> bf16 [N][K] in ws -------------
// W1T @0 (512x160), W2T @81920 (256x512), W3T @212992 (128x256),
// W4T @245760 (256x128, rows n>=251 zero-padded)
__global__ void prep_kernel(const float* __restrict__ W1, const float* __restrict__ W2,
                            const float* __restrict__ W3, const float* __restrict__ W4,
                            unsigned short* __restrict__ ws) {
  int i = blockIdx.x * PREP_THREADS + threadIdx.x;
  if (i < 81920) {
    int n = i / 160, k = i - n * 160;
    ws[i] = f2bf(W1[k * 512 + n]);
  } else if (i < 212992) {
    int j = i - 81920; int n = j >> 9, k = j & 511;
    ws[i] = f2bf(W2[k * 256 + n]);
  } else if (i < 245760) {
    int j = i - 212992; int n = j >> 8, k = j & 255;
    ws[i] = f2bf(W3[k * 128 + n]);
  } else if (i < 278528) {
    int j = i - 245760; int n = j >> 7, k = j & 127;
    ws[i] = (n < 251) ? f2bf(W4[k * 251 + n]) : (unsigned short)0;
  }
}

// LDS layout (bytes), aliased:
//  A @0     (32768): H1 bf16 [32][512] swz | H3 bf16 [32][128] swz @0
//                    | proj f32 [32][251] (zeroed AFTER GEMM4's H3 reads)
//  B @32768 (16384): X bf16 [32][160] swz  | H2 bf16 [32][256] swz
//  zs @49152 (1024), b4 @50176 (1024), red @51200 (1280)
#define OFF_A   0
#define OFF_B   32768
#define OFF_ZS  49152
#define OFF_B4  50176
#define OFF_RED 51200
#define LDS_TOTAL 52480

// GEMM: acc[ft][rt] += WT[fbase+ft*16+..][k] * H[rt*16+..][k]
// MFMA 16x16x32 bf16, A = weight rows (m=feature), B = act rows (n=batch row).
// D: lane&15 = batch row in tile, (lane>>4)*4+reg = feature in tile.
// All addressing hoisted: weight elem offsets per ft (imm ks*64B), LDS b-frag
// per-rt/per-parity byte bases (swizzle XOR can't fold past bit6 of ks*64,
// so even/odd ks get separate bases; imm advances by 128B).
template<int KD, int NFT>
__device__ __forceinline__ void gemm_w(const unsigned short* __restrict__ WT,
                                       const unsigned char* __restrict__ Hb,
                                       int fbase, f32x4 (&acc)[NFT][2]) {
  const int lane = threadIdx.x & 63;
  const int lm = lane & 15, kg = lane >> 4;
  int woff[NFT];
#pragma unroll
  for (int ft = 0; ft < NFT; ++ft)
    woff[ft] = (fbase + ft * 16 + lm) * KD + kg * 8;
  const unsigned char* bp[2][2];
#pragma unroll
  for (int rt = 0; rt < 2; ++rt) {
    const int r = rt * 16 + lm;
    const int swz = (r & 7) << 4;
    const int base = r * (KD * 2) + kg * 16;
    bp[rt][0] = Hb + ((base) ^ swz);
    bp[rt][1] = Hb + ((base + 64) ^ swz);
  }
#pragma unroll
  for (int ks = 0; ks < KD / 32; ++ks) {
    const int koff = (ks >> 1) * 128;
    const short8v b0 = *(const short8v*)(bp[0][ks & 1] + koff);
    const short8v b1 = *(const short8v*)(bp[1][ks & 1] + koff);
#pragma unroll
    for (int ft = 0; ft < NFT; ++ft) {
      const short8v a = *(const short8v*)(WT + woff[ft] + ks * 32);
      acc[ft][0] = __builtin_amdgcn_mfma_f32_16x16x32_bf16(a, b0, acc[ft][0], 0, 0, 0);
      acc[ft][1] = __builtin_amdgcn_mfma_f32_16x16x32_bf16(a, b1, acc[ft][1], 0, 0, 0);
    }
  }
}

// bias + LayerNorm + SiLU entirely in registers, then one packed b64 store
// per (ft, rt) into swizzled LDS [32][ND] bf16. 4 waves reduce via redL
// (stride 9 floats per row to dodge bank conflicts).
template<int ND, int NFT>
__device__ __forceinline__ void ln_silu_store(
    f32x4 (&acc)[NFT][2],
    const float* __restrict__ bias, const float* __restrict__ g,
    const float* __restrict__ be, unsigned char* __restrict__ Hb,
    float* __restrict__ redL, int fbase, int fq)
{
  const int lane = threadIdx.x & 63;
  const int lm = lane & 15, kg = lane >> 4;
  float s[2] = {0.f, 0.f}, q[2] = {0.f, 0.f};
#pragma unroll
  for (int ft = 0; ft < NFT; ++ft) {
    const int f0 = fbase + ft * 16 + kg * 4;
    const f32x4 bb = *(const f32x4*)(bias + f0);
#pragma unroll
    for (int rt = 0; rt < 2; ++rt)
#pragma unroll
      for (int rg = 0; rg < 4; ++rg) {
        float x = acc[ft][rt][rg] + bb[rg];
        acc[ft][rt][rg] = x;
        s[rt] += x; q[rt] += x * x;
      }
  }
#pragma unroll
  for (int rt = 0; rt < 2; ++rt) {
    s[rt] += __shfl_xor(s[rt], 16); s[rt] += __shfl_xor(s[rt], 32);
    q[rt] += __shfl_xor(q[rt], 16); q[rt] += __shfl_xor(q[rt], 32);
  }
  if (lane < 16) {
#pragma unroll
    for (int rt = 0; rt < 2; ++rt) {
      redL[(rt * 16 + lm) * 9 + fq * 2    ] = s[rt];
      redL[(rt * 16 + lm) * 9 + fq * 2 + 1] = q[rt];
    }
  }
  __syncthreads();
  float mean[2], rstd[2];
#pragma unroll
  for (int rt = 0; rt < 2; ++rt) {
    const int row = rt * 16 + lm;
    float S = 0.f, Q = 0.f;
#pragma unroll
    for (int w = 0; w < 4; ++w) {
      S += redL[row * 9 + w * 2];
      Q += redL[row * 9 + w * 2 + 1];
    }
    float m = S * (1.0f / ND);
    float v = Q * (1.0f / ND) - m * m;
    mean[rt] = m; rstd[rt] = rsqrtf(v + 1e-5f);
  }
#pragma unroll
  for (int ft = 0; ft < NFT; ++ft) {
    const int f0 = fbase + ft * 16 + kg * 4;
    const f32x4 g4 = *(const f32x4*)(g + f0);
    const f32x4 e4 = *(const f32x4*)(be + f0);
#pragma unroll
    for (int rt = 0; rt < 2; ++rt) {
      const int row = rt * 16 + lm;
      float h[4];
#pragma unroll
      for (int rg = 0; rg < 4; ++rg) {
        float y = (acc[ft][rt][rg] - mean[rt]) * rstd[rt] * g4[rg] + e4[rg];
        h[rg] = y * (1.0f / (1.0f + __expf(-y)));
      }
      uint2 w; w.x = pack2bf(h[0], h[1]); w.y = pack2bf(h[2], h[3]);
      int byte = row * (ND * 2) + f0 * 2;
      byte ^= ((row & 7) << 4);
      *(uint2*)(Hb + byte) = w;
    }
  }
}

__global__ __launch_bounds__(THREADS, 3) void fused_kernel(
    const float* __restrict__ obs, const float* __restrict__ actions,
    const float* __restrict__ rewards, const float* __restrict__ bootstrap,
    const float* __restrict__ discount, const float* __restrict__ q_support,
    const float* __restrict__ b1, const float* __restrict__ g1, const float* __restrict__ be1,
    const float* __restrict__ b2, const float* __restrict__ g2, const float* __restrict__ be2,
    const float* __restrict__ b3, const float* __restrict__ g3, const float* __restrict__ be3,
    const float* __restrict__ b4,
    const unsigned short* __restrict__ ws,
    float* __restrict__ out)
{
  __shared__ __align__(16) unsigned char smem[LDS_TOTAL];
  const int tid  = threadIdx.x;
  const int fq   = tid >> 6;          // wave = feature-quarter, 0..3
  const int lane = tid & 63;
  const int lm   = lane & 15;
  const int kg   = lane >> 4;
  const int row0 = blockIdx.x * 32;

  const unsigned short* W1T = ws;
  const unsigned short* W2T = ws + 81920;
  const unsigned short* W3T = ws + 212992;
  const unsigned short* W4T = ws + 245760;

  float* zsL  = (float*)(smem + OFF_ZS);
  float* b4L  = (float*)(smem + OFF_B4);
  float* redL = (float*)(smem + OFF_RED);

  // per-row scalars straight to registers (each lane owns rows rt*16+lm)
  float rw[2], bt[2], dc[2];
#pragma unroll
  for (int rt = 0; rt < 2; ++rt) {
    const int r = row0 + rt * 16 + lm;
    rw[rt] = rewards[r]; bt[rt] = bootstrap[r]; dc[rt] = discount[r];
  }

  // stage q_support / b4 (padded to 256, avoids OOB vector loads)
  zsL[tid] = (tid < 251) ? q_support[tid] : 0.f;
  b4L[tid] = (tid < 251) ? b4[tid] : 0.f;

  // stage X = concat(obs, actions) bf16 [32][160], swizzled (1280 uint2)
  {
    unsigned char* Xb = smem + OFF_B;
#pragma unroll
    for (int it = 0; it < 5; ++it) {
      const int qq = it * THREADS + tid;     // 0..1279, 40 float4 per row
      const int r  = qq / 40;
      const int c4 = (qq - r * 40) * 4;
      float4 v;
      if (c4 < 128) v = *(const float4*)(obs + (size_t)(row0 + r) * 128 + c4);
      else          v = *(const float4*)(actions + (size_t)(row0 + r) * 32 + (c4 - 128));
      uint2 w; w.x = pack2bf(v.x, v.y); w.y = pack2bf(v.z, v.w);
      int byte = r * 320 + c4 * 2;
      byte ^= ((r & 7) << 4);
      *(uint2*)(Xb + byte) = w;
    }
  }
  __syncthreads();

  // ---- layer 1: 512 feats, K=160; 128 feats/wave ----
  f32x4 acc1[8][2];
#pragma unroll
  for (int i = 0; i < 8; ++i) { acc1[i][0] = f32x4{0,0,0,0}; acc1[i][1] = f32x4{0,0,0,0}; }
  gemm_w<160, 8>(W1T, smem + OFF_B, fq * 128, acc1);
  ln_silu_store<512, 8>(acc1, b1, g1, be1, smem + OFF_A, redL, fq * 128, fq);
  __syncthreads();

  // ---- layer 2: 256 feats, K=512; 64 feats/wave ----
  f32x4 acc2[4][2];
#pragma unroll
  for (int i = 0; i < 4; ++i) { acc2[i][0] = f32x4{0,0,0,0}; acc2[i][1] = f32x4{0,0,0,0}; }
  gemm_w<512, 4>(W2T, smem + OFF_A, fq * 64, acc2);
  ln_silu_store<256, 4>(acc2, b2, g2, be2, smem + OFF_B, redL, fq * 64, fq);
  __syncthreads();

  // ---- layer 3: 128 feats, K=256; 32 feats/wave; H3 aliases dead H1 @A[0:8K]
  f32x4 acc3[2][2];
#pragma unroll
  for (int i = 0; i < 2; ++i) { acc3[i][0] = f32x4{0,0,0,0}; acc3[i][1] = f32x4{0,0,0,0}; }
  gemm_w<256, 2>(W3T, smem + OFF_B, fq * 32, acc3);
  ln_silu_store<128, 2>(acc3, b3, g3, be3, smem + OFF_A, redL, fq * 32, fq);
  __syncthreads();

  // ---- layer 4: logits, 256pad feats, K=128; 64 feats/wave ----
  f32x4 acc4[4][2];
#pragma unroll
  for (int i = 0; i < 4; ++i) { acc4[i][0] = f32x4{0,0,0,0}; acc4[i][1] = f32x4{0,0,0,0}; }
  gemm_w<128, 4>(W4T, smem + OFF_A, fq * 64, acc4);

  float lv[4][2][4];
#pragma unroll
  for (int ft = 0; ft < 4; ++ft) {
    const int f0 = fq * 64 + ft * 16 + kg * 4;
    const f32x4 bb = *(const f32x4*)(b4L + f0);
#pragma unroll
    for (int rt = 0; rt < 2; ++rt)
#pragma unroll
      for (int rg = 0; rg < 4; ++rg) {
        const int f = f0 + rg;
        lv[ft][rt][rg] = (f < 251) ? (acc4[ft][rt][rg] + bb[rg]) : -1e30f;
      }
  }

  // ---- softmax over 251 features per row (stride-5 padded reduction) ----
#pragma unroll
  for (int rt = 0; rt < 2; ++rt) {
    float m = lv[0][rt][0];
#pragma unroll
    for (int ft = 0; ft < 4; ++ft)
#pragma unroll
      for (int rg = 0; rg < 4; ++rg) m = fmaxf(m, lv[ft][rt][rg]);
    m = fmaxf(m, __shfl_xor(m, 16));
    m = fmaxf(m, __shfl_xor(m, 32));
    if (lane < 16) redL[(rt * 16 + lm) * 5 + fq] = m;
  }
  __syncthreads();   // also: all waves are past GEMM4's H3 reads

  // zero proj buffer (region A; overwrites H3 area too — H3 is dead now)
  float* projL = (float*)(smem + OFF_A);
  for (int i = tid; i < 32 * 251; i += THREADS) projL[i] = 0.f;

  float gm[2];
#pragma unroll
  for (int rt = 0; rt < 2; ++rt) {
    const int row = rt * 16 + lm;
    float m = redL[row * 5];
#pragma unroll
    for (int w = 1; w < 4; ++w) m = fmaxf(m, redL[row * 5 + w]);
    gm[rt] = m;
  }
  __syncthreads();   // redL reuse + proj zero visible
#pragma unroll
  for (int rt = 0; rt < 2; ++rt) {
    float E = 0.f;
#pragma unroll
    for (int ft = 0; ft < 4; ++ft)
#pragma unroll
      for (int rg = 0; rg < 4; ++rg) {
        float e = __expf(lv[ft][rt][rg] - gm[rt]);
        lv[ft][rt][rg] = e;
        E += e;
      }
    E += __shfl_xor(E, 16); E += __shfl_xor(E, 32);
    if (lane < 16) redL[(rt * 16 + lm) * 5 + fq] = E;
  }
  __syncthreads();
  float inv[2];
#pragma unroll
  for (int rt = 0; rt < 2; ++rt) {
    const int row = rt * 16 + lm;
    float E = 0.f;
#pragma unroll
    for (int w = 0; w < 4; ++w) E += redL[row * 5 + w];
    inv[rt] = 1.0f / E;
  }

  // ---- C51 projection scatter (bit-exact bin math vs numpy) ----
  constexpr float DZF = 20.0f / 250.0f;
#pragma unroll
  for (int ft = 0; ft < 4; ++ft) {
    const int f0 = fq * 64 + ft * 16 + kg * 4;
    const f32x4 z4 = *(const f32x4*)(zsL + f0);
#pragma unroll
    for (int rt = 0; rt < 2; ++rt) {
      const int base = (rt * 16 + lm) * 251;
      const float bd = __fmul_rn(bt[rt], dc[rt]);
#pragma unroll
      for (int rg = 0; rg < 4; ++rg) {
        const int f = f0 + rg;
        if (f < 251) {
          const float p = lv[ft][rt][rg] * inv[rt];
          float t = __fadd_rn(rw[rt], __fmul_rn(bd, z4[rg]));
          t = fminf(fmaxf(t, -10.0f), 10.0f);
          const float bfr = __fdiv_rn(__fsub_rn(t, -10.0f), DZF);
          const float fl = floorf(bfr), fu = ceilf(bfr);
          int l = (int)fl, u = (int)fu;
          if (fl == fu) { if (l > 0) --l; else ++u; }
          atomicAdd(projL + base + l, p * ((float)u - bfr));
          atomicAdd(projL + base + u, p * (bfr - (float)l));
        }
      }
    }
  }
  __syncthreads();

  // ---- write out: block slice contiguous (32*251 floats = 2008 float4) ----
  const float4* ps = (const float4*)projL;
  float4* po = (float4*)(out + (size_t)row0 * 251);
  for (int i = tid; i < 2008; i += THREADS) po[i] = ps[i];
}

extern "C" void kernel_launch(void* const* d_in, const int* in_sizes, int n_in,
                              void* d_out, int out_size, void* d_ws, size_t ws_size,
                              hipStream_t stream) {
  const float* obs  = (const float*)d_in[0];
  const float* act  = (const float*)d_in[1];
  const float* rew  = (const float*)d_in[2];
  const float* boot = (const float*)d_in[3];
  const float* disc = (const float*)d_in[4];
  const float* zs   = (const float*)d_in[5];
  const float* W1   = (const float*)d_in[6];
  const float* b1   = (const float*)d_in[7];
  const float* g1   = (const float*)d_in[8];
  const float* be1  = (const float*)d_in[9];
  const float* W2   = (const float*)d_in[10];
  const float* b2   = (const float*)d_in[11];
  const float* g2   = (const float*)d_in[12];
  const float* be2  = (const float*)d_in[13];
  const float* W3   = (const float*)d_in[14];
  const float* b3   = (const float*)d_in[15];
  const float* g3   = (const float*)d_in[16];
  const float* be3  = (const float*)d_in[17];
  const float* W4   = (const float*)d_in[18];
  const float* b4   = (const float*)d_in[19];
  unsigned short* wsp = (unsigned short*)d_ws;

  const int Bn = in_sizes[2];          // batch = 131072
  prep_kernel<<<(278528 + PREP_THREADS - 1) / PREP_THREADS, PREP_THREADS, 0, stream>>>(
      W1, W2, W3, W4, wsp);
  fused_kernel<<<Bn / 32, THREADS, 0, stream>>>(obs, act, rew, boot, disc, zs,
      b1, g1, be1, b2, g2, be2, b3, g3, be3, b4, wsp, (float*)d_out);
}

// Round 5
// 482.829 us; speedup vs baseline: 1.1894x; 1.0521x over previous
//
#include <hip/hip_runtime.h>

// C51 distributional Q target: operand-swapped MFMA (D = W * X^T), each lane
// owns 4 consecutive FEATURES of one batch ROW; LN/SiLU/softmax in registers.
// R5: (1) single time-multiplexed 32KB LDS region (X->H1->H2->H3->proj),
// total 36.1KB -> 4 blocks/CU (16 waves, 50% occ cap); (2) explicit depth-1
// double-buffered pipeline in gemm_w (a-frags from L2, b-frags from LDS),
// launch_bounds(256,4) => VGPR cap 128.

#define THREADS 256
#define PREP_THREADS 256

typedef __attribute__((ext_vector_type(8))) short short8v;
typedef __attribute__((ext_vector_type(4))) float f32x4;

__device__ __forceinline__ unsigned short f2bf(float f) {
  union { float f; unsigned u; } v; v.f = f;
  unsigned u = v.u;
  u += 0x7fffu + ((u >> 16) & 1u);   // RNE
  return (unsigned short)(u >> 16);
}
__device__ __forceinline__ unsigned pack2bf(float a, float b) {
  return (unsigned)f2bf(a) | ((unsigned)f2bf(b) << 16);
}

// ---------------- prep: weights fp32 [K][N] -> bf16 [N][K] in ws -------------
// W1T @0 (512x160), W2T @81920 (256x512), W3T @212992 (128x256),
// W4T @245760 (256x128, rows n>=251 zero-padded)
__global__ void prep_kernel(const float* __restrict__ W1, const float* __restrict__ W2,
                            const float* __restrict__ W3, const float* __restrict__ W4,
                            unsigned short* __restrict__ ws) {
  int i = blockIdx.x * PREP_THREADS + threadIdx.x;
  if (i < 81920) {
    int n = i / 160, k = i - n * 160;
    ws[i] = f2bf(W1[k * 512 + n]);
  } else if (i < 212992) {
    int j = i - 81920; int n = j >> 9, k = j & 511;
    ws[i] = f2bf(W2[k * 256 + n]);
  } else if (i < 245760) {
    int j = i - 212992; int n = j >> 8, k = j & 255;
    ws[i] = f2bf(W3[k * 128 + n]);
  } else if (i < 278528) {
    int j = i - 245760; int n = j >> 7, k = j & 127;
    ws[i] = (n < 251) ? f2bf(W4[k * 251 + n]) : (unsigned short)0;
  }
}

// LDS layout (bytes). ONE time-multiplexed 32KB region R @0:
//   X bf16 [32][160] swz  (stage..GEMM1)
//   H1 bf16 [32][512] swz (written post-GEMM1 internal barrier, read GEMM2)
//   H2 bf16 [32][256] swz (written post-GEMM2 internal barrier, read GEMM3)
//   H3 bf16 [32][128] swz (written post-GEMM3 internal barrier, read GEMM4)
//   proj f32 [32][251]    (zeroed after GEMM4+barrier)
// Each overwrite is protected by the LN reduction's internal __syncthreads,
// which all waves reach only after finishing the previous region reads.
#define OFF_R   0
#define OFF_ZS  32768
#define OFF_B4  33792
#define OFF_RED 34816
#define LDS_TOTAL 36096

// GEMM: acc[ft][rt] += WT[fbase+ft*16+..][k] * H[rt*16+..][k]
// MFMA 16x16x32 bf16, A = weight rows (m=feature), B = act rows (n=batch row).
// D: lane&15 = batch row in tile, (lane>>4)*4+reg = feature in tile.
// Explicit depth-1 double-buffer: item (ks,g) MFMAs overlap loads of item+1.
// All buffer indices are compile-time after full unroll (no scratch).
template<int KD, int NFT>
__device__ __forceinline__ void gemm_w(const unsigned short* __restrict__ WT,
                                       const unsigned char* __restrict__ Hb,
                                       int fbase, f32x4 (&acc)[NFT][2]) {
  const int lane = threadIdx.x & 63;
  const int lm = lane & 15, kg = lane >> 4;
  constexpr int KS  = KD / 32;
  constexpr int G   = (NFT > 4) ? 2 : 1;   // ft groups (cap live a-frags at 4)
  constexpr int FPG = NFT / G;
  constexpr int NIT = KS * G;

  int woff[NFT];
#pragma unroll
  for (int ft = 0; ft < NFT; ++ft)
    woff[ft] = (fbase + ft * 16 + lm) * KD + kg * 8;

  // b-frag LDS byte offsets: per-rt, per-ks-parity (swizzle XOR folds over
  // bit6 of ks*64; higher bits advance linearly by 128B per ks pair).
  int boff[2][2];
#pragma unroll
  for (int rt = 0; rt < 2; ++rt) {
    const int r = rt * 16 + lm;
    const int swz = (r & 7) << 4;
    const int base = r * (KD * 2) + kg * 16;
    boff[rt][0] = base ^ swz;
    boff[rt][1] = (base + 64) ^ swz;
  }

  short8v abuf[2][FPG];
  short8v bbuf[2][2];
#pragma unroll
  for (int rt = 0; rt < 2; ++rt)
    bbuf[0][rt] = *(const short8v*)(Hb + boff[rt][0]);
#pragma unroll
  for (int f = 0; f < FPG; ++f)
    abuf[0][f] = *(const short8v*)(WT + woff[f]);

#pragma unroll
  for (int it = 0; it < NIT; ++it) {
    const int ks = it / G, g = it % G;
    const int cur = it & 1, nxt = cur ^ 1;
    if (it + 1 < NIT) {
      const int nit = it + 1;
      const int nks = nit / G, ng = nit % G;
      if (ng == 0) {
        const int koff = (nks >> 1) * 128;
#pragma unroll
        for (int rt = 0; rt < 2; ++rt)
          bbuf[nks & 1][rt] = *(const short8v*)(Hb + boff[rt][nks & 1] + koff);
      }
#pragma unroll
      for (int f = 0; f < FPG; ++f)
        abuf[nxt][f] = *(const short8v*)(WT + woff[ng * FPG + f] + nks * 32);
    }
#pragma unroll
    for (int f = 0; f < FPG; ++f) {
      const int ft = g * FPG + f;
      acc[ft][0] = __builtin_amdgcn_mfma_f32_16x16x32_bf16(abuf[cur][f], bbuf[ks & 1][0], acc[ft][0], 0, 0, 0);
      acc[ft][1] = __builtin_amdgcn_mfma_f32_16x16x32_bf16(abuf[cur][f], bbuf[ks & 1][1], acc[ft][1], 0, 0, 0);
    }
  }
}

// bias + LayerNorm + SiLU entirely in registers, then one packed b64 store
// per (ft, rt) into swizzled LDS [32][ND] bf16. 4 waves reduce via redL
// (stride 9 floats per row). Internal barrier doubles as the region-reuse
// fence: H-store below only happens after ALL waves finished the previous
// GEMM's reads of this region.
template<int ND, int NFT>
__device__ __forceinline__ void ln_silu_store(
    f32x4 (&acc)[NFT][2],
    const float* __restrict__ bias, const float* __restrict__ g,
    const float* __restrict__ be, unsigned char* __restrict__ Hb,
    float* __restrict__ redL, int fbase, int fq)
{
  const int lane = threadIdx.x & 63;
  const int lm = lane & 15, kg = lane >> 4;
  float s[2] = {0.f, 0.f}, q[2] = {0.f, 0.f};
#pragma unroll
  for (int ft = 0; ft < NFT; ++ft) {
    const int f0 = fbase + ft * 16 + kg * 4;
    const f32x4 bb = *(const f32x4*)(bias + f0);
#pragma unroll
    for (int rt = 0; rt < 2; ++rt)
#pragma unroll
      for (int rg = 0; rg < 4; ++rg) {
        float x = acc[ft][rt][rg] + bb[rg];
        acc[ft][rt][rg] = x;
        s[rt] += x; q[rt] += x * x;
      }
  }
#pragma unroll
  for (int rt = 0; rt < 2; ++rt) {
    s[rt] += __shfl_xor(s[rt], 16); s[rt] += __shfl_xor(s[rt], 32);
    q[rt] += __shfl_xor(q[rt], 16); q[rt] += __shfl_xor(q[rt], 32);
  }
  if (lane < 16) {
#pragma unroll
    for (int rt = 0; rt < 2; ++rt) {
      redL[(rt * 16 + lm) * 9 + fq * 2    ] = s[rt];
      redL[(rt * 16 + lm) * 9 + fq * 2 + 1] = q[rt];
    }
  }
  __syncthreads();
  float mean[2], rstd[2];
#pragma unroll
  for (int rt = 0; rt < 2; ++rt) {
    const int row = rt * 16 + lm;
    float S = 0.f, Q = 0.f;
#pragma unroll
    for (int w = 0; w < 4; ++w) {
      S += redL[row * 9 + w * 2];
      Q += redL[row * 9 + w * 2 + 1];
    }
    float m = S * (1.0f / ND);
    float v = Q * (1.0f / ND) - m * m;
    mean[rt] = m; rstd[rt] = rsqrtf(v + 1e-5f);
  }
#pragma unroll
  for (int ft = 0; ft < NFT; ++ft) {
    const int f0 = fbase + ft * 16 + kg * 4;
    const f32x4 g4 = *(const f32x4*)(g + f0);
    const f32x4 e4 = *(const f32x4*)(be + f0);
#pragma unroll
    for (int rt = 0; rt < 2; ++rt) {
      const int row = rt * 16 + lm;
      float h[4];
#pragma unroll
      for (int rg = 0; rg < 4; ++rg) {
        float y = (acc[ft][rt][rg] - mean[rt]) * rstd[rt] * g4[rg] + e4[rg];
        h[rg] = y * (1.0f / (1.0f + __expf(-y)));
      }
      uint2 w; w.x = pack2bf(h[0], h[1]); w.y = pack2bf(h[2], h[3]);
      int byte = row * (ND * 2) + f0 * 2;
      byte ^= ((row & 7) << 4);
      *(uint2*)(Hb + byte) = w;
    }
  }
}

__global__ __launch_bounds__(THREADS, 4) void fused_kernel(
    const float* __restrict__ obs, const float* __restrict__ actions,
    const float* __restrict__ rewards, const float* __restrict__ bootstrap,
    const float* __restrict__ discount, const float* __restrict__ q_support,
    const float* __restrict__ b1, const float* __restrict__ g1, const float* __restrict__ be1,
    const float* __restrict__ b2, const float* __restrict__ g2, const float* __restrict__ be2,
    const float* __restrict__ b3, const float* __restrict__ g3, const float* __restrict__ be3,
    const float* __restrict__ b4,
    const unsigned short* __restrict__ ws,
    float* __restrict__ out)
{
  __shared__ __align__(16) unsigned char smem[LDS_TOTAL];
  const int tid  = threadIdx.x;
  const int fq   = tid >> 6;          // wave = feature-quarter, 0..3
  const int lane = tid & 63;
  const int lm   = lane & 15;
  const int kg   = lane >> 4;
  const int row0 = blockIdx.x * 32;

  const unsigned short* W1T = ws;
  const unsigned short* W2T = ws + 81920;
  const unsigned short* W3T = ws + 212992;
  const unsigned short* W4T = ws + 245760;

  float* zsL  = (float*)(smem + OFF_ZS);
  float* b4L  = (float*)(smem + OFF_B4);
  float* redL = (float*)(smem + OFF_RED);

  // per-row scalars straight to registers (each lane owns rows rt*16+lm)
  float rw[2], bt[2], dc[2];
#pragma unroll
  for (int rt = 0; rt < 2; ++rt) {
    const int r = row0 + rt * 16 + lm;
    rw[rt] = rewards[r]; bt[rt] = bootstrap[r]; dc[rt] = discount[r];
  }

  // stage q_support / b4 (padded to 256, avoids OOB vector loads)
  zsL[tid] = (tid < 251) ? q_support[tid] : 0.f;
  b4L[tid] = (tid < 251) ? b4[tid] : 0.f;

  // stage X = concat(obs, actions) bf16 [32][160], swizzled (1280 uint2)
  {
    unsigned char* Xb = smem + OFF_R;
#pragma unroll
    for (int it = 0; it < 5; ++it) {
      const int qq = it * THREADS + tid;     // 0..1279, 40 float4 per row
      const int r  = qq / 40;
      const int c4 = (qq - r * 40) * 4;
      float4 v;
      if (c4 < 128) v = *(const float4*)(obs + (size_t)(row0 + r) * 128 + c4);
      else          v = *(const float4*)(actions + (size_t)(row0 + r) * 32 + (c4 - 128));
      uint2 w; w.x = pack2bf(v.x, v.y); w.y = pack2bf(v.z, v.w);
      int byte = r * 320 + c4 * 2;
      byte ^= ((r & 7) << 4);
      *(uint2*)(Xb + byte) = w;
    }
  }
  __syncthreads();

  // ---- layer 1: 512 feats, K=160; 128 feats/wave ----
  f32x4 acc1[8][2];
#pragma unroll
  for (int i = 0; i < 8; ++i) { acc1[i][0] = f32x4{0,0,0,0}; acc1[i][1] = f32x4{0,0,0,0}; }
  gemm_w<160, 8>(W1T, smem + OFF_R, fq * 128, acc1);
  ln_silu_store<512, 8>(acc1, b1, g1, be1, smem + OFF_R, redL, fq * 128, fq);
  __syncthreads();

  // ---- layer 2: 256 feats, K=512; 64 feats/wave ----
  f32x4 acc2[4][2];
#pragma unroll
  for (int i = 0; i < 4; ++i) { acc2[i][0] = f32x4{0,0,0,0}; acc2[i][1] = f32x4{0,0,0,0}; }
  gemm_w<512, 4>(W2T, smem + OFF_R, fq * 64, acc2);
  ln_silu_store<256, 4>(acc2, b2, g2, be2, smem + OFF_R, redL, fq * 64, fq);
  __syncthreads();

  // ---- layer 3: 128 feats, K=256; 32 feats/wave ----
  f32x4 acc3[2][2];
#pragma unroll
  for (int i = 0; i < 2; ++i) { acc3[i][0] = f32x4{0,0,0,0}; acc3[i][1] = f32x4{0,0,0,0}; }
  gemm_w<256, 2>(W3T, smem + OFF_R, fq * 32, acc3);
  ln_silu_store<128, 2>(acc3, b3, g3, be3, smem + OFF_R, redL, fq * 32, fq);
  __syncthreads();

  // ---- layer 4: logits, 256pad feats, K=128; 64 feats/wave ----
  f32x4 acc4[4][2];
#pragma unroll
  for (int i = 0; i < 4; ++i) { acc4[i][0] = f32x4{0,0,0,0}; acc4[i][1] = f32x4{0,0,0,0}; }
  gemm_w<128, 4>(W4T, smem + OFF_R, fq * 64, acc4);

  float lv[4][2][4];
#pragma unroll
  for (int ft = 0; ft < 4; ++ft) {
    const int f0 = fq * 64 + ft * 16 + kg * 4;
    const f32x4 bb = *(const f32x4*)(b4L + f0);
#pragma unroll
    for (int rt = 0; rt < 2; ++rt)
#pragma unroll
      for (int rg = 0; rg < 4; ++rg) {
        const int f = f0 + rg;
        lv[ft][rt][rg] = (f < 251) ? (acc4[ft][rt][rg] + bb[rg]) : -1e30f;
      }
  }

  // ---- softmax over 251 features per row (stride-5 padded reduction) ----
#pragma unroll
  for (int rt = 0; rt < 2; ++rt) {
    float m = lv[0][rt][0];
#pragma unroll
    for (int ft = 0; ft < 4; ++ft)
#pragma unroll
      for (int rg = 0; rg < 4; ++rg) m = fmaxf(m, lv[ft][rt][rg]);
    m = fmaxf(m, __shfl_xor(m, 16));
    m = fmaxf(m, __shfl_xor(m, 32));
    if (lane < 16) redL[(rt * 16 + lm) * 5 + fq] = m;
  }
  __syncthreads();   // all waves past GEMM4's H3 reads; redL max visible

  // zero proj buffer (region R; overwrites H3 — dead now)
  float* projL = (float*)(smem + OFF_R);
  for (int i = tid; i < 32 * 251; i += THREADS) projL[i] = 0.f;

  float gm[2];
#pragma unroll
  for (int rt = 0; rt < 2; ++rt) {
    const int row = rt * 16 + lm;
    float m = redL[row * 5];
#pragma unroll
    for (int w = 1; w < 4; ++w) m = fmaxf(m, redL[row * 5 + w]);
    gm[rt] = m;
  }
  __syncthreads();   // redL reuse + proj zeros visible
#pragma unroll
  for (int rt = 0; rt < 2; ++rt) {
    float E = 0.f;
#pragma unroll
    for (int ft = 0; ft < 4; ++ft)
#pragma unroll
      for (int rg = 0; rg < 4; ++rg) {
        float e = __expf(lv[ft][rt][rg] - gm[rt]);
        lv[ft][rt][rg] = e;
        E += e;
      }
    E += __shfl_xor(E, 16); E += __shfl_xor(E, 32);
    if (lane < 16) redL[(rt * 16 + lm) * 5 + fq] = E;
  }
  __syncthreads();
  float inv[2];
#pragma unroll
  for (int rt = 0; rt < 2; ++rt) {
    const int row = rt * 16 + lm;
    float E = 0.f;
#pragma unroll
    for (int w = 0; w < 4; ++w) E += redL[row * 5 + w];
    inv[rt] = 1.0f / E;
  }

  // ---- C51 projection scatter (bit-exact bin math vs numpy) ----
  constexpr float DZF = 20.0f / 250.0f;
#pragma unroll
  for (int ft = 0; ft < 4; ++ft) {
    const int f0 = fq * 64 + ft * 16 + kg * 4;
    const f32x4 z4 = *(const f32x4*)(zsL + f0);
#pragma unroll
    for (int rt = 0; rt < 2; ++rt) {
      const int base = (rt * 16 + lm) * 251;
      const float bd = __fmul_rn(bt[rt], dc[rt]);
#pragma unroll
      for (int rg = 0; rg < 4; ++rg) {
        const int f = f0 + rg;
        if (f < 251) {
          const float p = lv[ft][rt][rg] * inv[rt];
          float t = __fadd_rn(rw[rt], __fmul_rn(bd, z4[rg]));
          t = fminf(fmaxf(t, -10.0f), 10.0f);
          const float bfr = __fdiv_rn(__fsub_rn(t, -10.0f), DZF);
          const float fl = floorf(bfr), fu = ceilf(bfr);
          int l = (int)fl, u = (int)fu;
          if (fl == fu) { if (l > 0) --l; else ++u; }
          atomicAdd(projL + base + l, p * ((float)u - bfr));
          atomicAdd(projL + base + u, p * (bfr - (float)l));
        }
      }
    }
  }
  __syncthreads();

  // ---- write out: block slice contiguous (32*251 floats = 2008 float4) ----
  const float4* ps = (const float4*)projL;
  float4* po = (float4*)(out + (size_t)row0 * 251);
  for (int i = tid; i < 2008; i += THREADS) po[i] = ps[i];
}

extern "C" void kernel_launch(void* const* d_in, const int* in_sizes, int n_in,
                              void* d_out, int out_size, void* d_ws, size_t ws_size,
                              hipStream_t stream) {
  const float* obs  = (const float*)d_in[0];
  const float* act  = (const float*)d_in[1];
  const float* rew  = (const float*)d_in[2];
  const float* boot = (const float*)d_in[3];
  const float* disc = (const float*)d_in[4];
  const float* zs   = (const float*)d_in[5];
  const float* W1   = (const float*)d_in[6];
  const float* b1   = (const float*)d_in[7];
  const float* g1   = (const float*)d_in[8];
  const float* be1  = (const float*)d_in[9];
  const float* W2   = (const float*)d_in[10];
  const float* b2   = (const float*)d_in[11];
  const float* g2   = (const float*)d_in[12];
  const float* be2  = (const float*)d_in[13];
  const float* W3   = (const float*)d_in[14];
  const float* b3   = (const float*)d_in[15];
  const float* g3   = (const float*)d_in[16];
  const float* be3  = (const float*)d_in[17];
  const float* W4   = (const float*)d_in[18];
  const float* b4   = (const float*)d_in[19];
  unsigned short* wsp = (unsigned short*)d_ws;

  const int Bn = in_sizes[2];          // batch = 131072
  prep_kernel<<<(278528 + PREP_THREADS - 1) / PREP_THREADS, PREP_THREADS, 0, stream>>>(
      W1, W2, W3, W4, wsp);
  fused_kernel<<<Bn / 32, THREADS, 0, stream>>>(obs, act, rew, boot, disc, zs,
      b1, g1, be1, b2, g2, be2, b3, g3, be3, b4, wsp, (float*)d_out);
}